// Round 9
// baseline (799.567 us; speedup 1.0000x reference)
//
#include <hip/hip_runtime.h>
#include <math.h>

#define MM 100     // mentions
#define CC 30      // candidates
#define DE 300     // embedding dim
#define NK 3       // relation types
#define NLOOP 10   // LBP iterations
#define INV_SQRT_D 0.05773502691896258f   // 1/sqrt(300)

typedef __attribute__((ext_vector_type(8))) short bf16x8;
typedef __attribute__((ext_vector_type(4))) float f32x4;

// ws layout (floats): same as R6/R7/R8
//  f@0 g@30000 psi@60000 t@63000 a@153000
//  REH@183000 REL@1719000 (bf16 [k][i][32][320] padded hi/lo)
//  entH@3255000 entL@3767000 (bf16 [j][32][320])
//  phi@4279000  mbarA@13279000 mbarB@13579000 stot@13879000

__device__ inline void bf16split(float x, short* hi, short* lo) {
  unsigned u  = __float_as_uint(x);
  unsigned hu = u & 0xFFFF0000u;
  float xh = __uint_as_float(hu);
  float rl = x - xh;
  unsigned lu = __float_as_uint(rl);
  lu += 0x7FFFu + ((lu >> 16) & 1u);
  *hi = (short)(hu >> 16);
  *lo = (short)(lu >> 16);
}

// ---------- f = tanh(fmc_in @ W + b) ----------
__global__ __launch_bounds__(256) void k_f(const float* __restrict__ fmc,
                                           const float* __restrict__ W,
                                           const float* __restrict__ b,
                                           float* __restrict__ f) {
  __shared__ float xs[3*DE];
  int m = blockIdx.x;
  for (int e = threadIdx.x; e < 3*DE; e += 256) xs[e] = fmc[m*3*DE + e];
  __syncthreads();
  for (int d = threadIdx.x; d < DE; d += 256) {
    float acc = b[d];
    for (int e = 0; e < 3*DE; ++e) acc = fmaf(xs[e], W[e*DE + d], acc);
    f[m*DE + d] = tanhf(acc);
  }
}

// ---------- g[m,d] = sum_e B[d,e] f[m,e] ----------
__global__ __launch_bounds__(256) void k_g(const float* __restrict__ Bm,
                                           const float* __restrict__ f,
                                           float* __restrict__ g) {
  __shared__ float fs[DE];
  int m = blockIdx.x;
  for (int e = threadIdx.x; e < DE; e += 256) fs[e] = f[m*DE + e];
  __syncthreads();
  for (int d = threadIdx.x; d < DE; d += 256) {
    float acc = 0.f;
    const float* Br = Bm + d*DE;
    for (int e = 0; e < DE; ++e) acc = fmaf(Br[e], fs[e], acc);
    g[m*DE + d] = acc;
  }
}

// ---------- psi[m,c] = ent[m,c,:] . g[m,:] ----------
__global__ __launch_bounds__(256) void k_psi(const float* __restrict__ ent,
                                             const float* __restrict__ g,
                                             float* __restrict__ psi) {
  __shared__ float gs[DE];
  int m = blockIdx.x;
  for (int e = threadIdx.x; e < DE; e += 256) gs[e] = g[m*DE + e];
  __syncthreads();
  int wave = threadIdx.x >> 6, lane = threadIdx.x & 63;
  for (int c = wave; c < CC; c += 4) {
    float acc = 0.f;
    const float* er = ent + (m*CC + c)*DE;
    for (int d = lane; d < DE; d += 64) acc = fmaf(er[d], gs[d], acc);
    #pragma unroll
    for (int off = 32; off; off >>= 1) acc += __shfl_down(acc, off, 64);
    if (lane == 0) psi[m*CC + c] = acc;
  }
}

// ---------- t[k,j,d] = sum_e D[k,d,e] f[j,e] ----------
__global__ __launch_bounds__(256) void k_t(const float* __restrict__ Dm,
                                           const float* __restrict__ f,
                                           float* __restrict__ t) {
  __shared__ float fs[DE];
  int k = blockIdx.x / MM, j = blockIdx.x % MM;
  for (int e = threadIdx.x; e < DE; e += 256) fs[e] = f[j*DE + e];
  __syncthreads();
  for (int d = threadIdx.x; d < DE; d += 256) {
    float acc = 0.f;
    const float* Dr = Dm + (k*DE + d)*DE;
    for (int e = 0; e < DE; ++e) acc = fmaf(Dr[e], fs[e], acc);
    t[(k*MM + j)*DE + d] = acc;
  }
}

// ---------- a[i,j,k] = softmax_k( f_i . t[k,j,:] / sqrt(D) ) ----------
__global__ __launch_bounds__(256) void k_a(const float* __restrict__ f,
                                           const float* __restrict__ t,
                                           float* __restrict__ a) {
  __shared__ float fs[DE];
  int i = blockIdx.x;
  for (int e = threadIdx.x; e < DE; e += 256) fs[e] = f[i*DE + e];
  __syncthreads();
  int wave = threadIdx.x >> 6, lane = threadIdx.x & 63;
  for (int j = wave; j < MM; j += 4) {
    float sk[NK];
    #pragma unroll
    for (int k = 0; k < NK; ++k) {
      float acc = 0.f;
      const float* tr = t + (k*MM + j)*DE;
      for (int d = lane; d < DE; d += 64) acc = fmaf(fs[d], tr[d], acc);
      #pragma unroll
      for (int off = 32; off; off >>= 1) acc += __shfl_down(acc, off, 64);
      sk[k] = acc;
    }
    if (lane == 0) {
      float s0 = sk[0]*INV_SQRT_D, s1 = sk[1]*INV_SQRT_D, s2 = sk[2]*INV_SQRT_D;
      float mx = fmaxf(s0, fmaxf(s1, s2));
      float e0 = expf(s0 - mx), e1 = expf(s1 - mx), e2 = expf(s2 - mx);
      float inv = 1.f / (e0 + e1 + e2);
      float* ar = a + (i*MM + j)*NK;
      ar[0] = e0*inv; ar[1] = e1*inv; ar[2] = e2*inv;
    }
  }
}

// ---------- split ent -> padded bf16 hi/lo [j][32][320] ----------
__global__ __launch_bounds__(256) void k_esplit(const float* __restrict__ ent,
                                                short* __restrict__ entH,
                                                short* __restrict__ entL) {
  int j = blockIdx.x;
  for (int idx = threadIdx.x; idx < 32*320; idx += 256) {
    int q = idx / 320, kk = idx % 320;
    float x = (q < CC && kk < DE) ? ent[(j*CC + q)*DE + kk] : 0.f;
    short h, l;
    bf16split(x, &h, &l);
    entH[(j*32 + q)*320 + kk] = h;
    entL[(j*32 + q)*320 + kk] = l;
  }
}

// ---------- RE GEMM: out = split_bf16( ent_flat[3000,300] @ R_k^T ), padded ----------
__global__ __launch_bounds__(256) void k_re(const float* __restrict__ R,
                                            const float* __restrict__ ent,
                                            short* __restrict__ REH,
                                            short* __restrict__ REL) {
  __shared__ float4 As4[128*5];
  __shared__ float4 Bs4[64*5];
  float* As = (float*)As4;
  float* Bs = (float*)Bs4;

  const int k  = blockIdx.z;
  const int r0 = blockIdx.y * 128;
  const int d0 = blockIdx.x * 64;
  const int tx = threadIdx.x & 15;
  const int ty = threadIdx.x >> 4;
  const float* A  = ent;
  const float* Bk = R + k*DE*DE;

  float acc[8][4];
  #pragma unroll
  for (int r = 0; r < 8; ++r)
    #pragma unroll
    for (int s = 0; s < 4; ++s) acc[r][s] = 0.f;

  for (int e0 = 0; e0 < DE; e0 += 20) {
    #pragma unroll
    for (int it = 0; it < 10; ++it) {
      int idx = threadIdx.x + it*256;
      int row = idx / 20, e = idx % 20;
      int gr = r0 + row;
      As[idx] = (gr < MM*CC) ? A[gr*DE + e0 + e] : 0.f;
    }
    #pragma unroll
    for (int it = 0; it < 5; ++it) {
      int idx = threadIdx.x + it*256;
      int row = idx / 20, e = idx % 20;
      int gd = d0 + row;
      Bs[idx] = (gd < DE) ? Bk[gd*DE + e0 + e] : 0.f;
    }
    __syncthreads();

    #pragma unroll
    for (int v = 0; v < 5; ++v) {
      float4 av[8], bv[4];
      #pragma unroll
      for (int r = 0; r < 8; ++r) av[r] = As4[(ty + 16*r)*5 + v];
      #pragma unroll
      for (int s = 0; s < 4; ++s) bv[s] = Bs4[(tx + 16*s)*5 + v];
      #pragma unroll
      for (int r = 0; r < 8; ++r)
        #pragma unroll
        for (int s = 0; s < 4; ++s) {
          acc[r][s] = fmaf(av[r].x, bv[s].x, acc[r][s]);
          acc[r][s] = fmaf(av[r].y, bv[s].y, acc[r][s]);
          acc[r][s] = fmaf(av[r].z, bv[s].z, acc[r][s]);
          acc[r][s] = fmaf(av[r].w, bv[s].w, acc[r][s]);
        }
    }
    __syncthreads();
  }

  #pragma unroll
  for (int r = 0; r < 8; ++r) {
    int gr = r0 + ty + 16*r;
    if (gr < MM*CC) {
      int i = gr / CC, p = gr % CC;
      #pragma unroll
      for (int s = 0; s < 4; ++s) {
        int gd = d0 + tx + 16*s;
        if (gd < DE) {
          size_t idx = (((size_t)k*MM + i)*32 + p)*320 + gd;
          short h, l;
          bf16split(acc[r][s], &h, &l);
          REH[idx] = h;
          REL[idx] = l;
        }
      }
    }
  }
}

// ---------- phi via MFMA: LDS-resident A, fragment-contiguous layout ----------
// Block = (i, 50-j half), 512 thr = 8 waves, each wave 2 j per pass.
// A(i) staged once: 120 frags (6 surf x 2 rowblk x 10 c) x 1024 B, lane-ordered
// -> every ds_read_b128 is a contiguous 1024 B wave read (0 bank conflicts).
// B from global (XCD-pinned: half = bs&1 -> even XCDs j<50, odd j>=50).
__global__ __launch_bounds__(512, 2) void k_phi5(const float* __restrict__ a,
                                                 const short* __restrict__ REH,
                                                 const short* __restrict__ REL,
                                                 const short* __restrict__ entH,
                                                 const short* __restrict__ entL,
                                                 float* __restrict__ phi) {
  __shared__ short As[120*512];   // 122,880 B
  const int bs = blockIdx.x;
  const int i = bs >> 1;
  const int jbase = (bs & 1) * 50;
  const int tid = threadIdx.x;

  // ---- stage A: frag fid = (surf*2 + rb)*10 + c; elem = lane*8 shorts ----
  for (int u = tid; u < 120*64; u += 512) {
    const int fid = u >> 6, lp = u & 63;
    const int surf = fid / 20, rem = fid % 20;
    const int rb = rem / 10, c = rem % 10;
    const int rel = (surf < 3) ? surf : surf - 3;
    const short* src = (surf < 3) ? REH : REL;
    const int rw = lp & 15, g = lp >> 4;
    const int4 v = *(const int4*)(src + ((rel*MM + i)*32 + rb*16 + rw)*320 + c*32 + g*8);
    *(int4*)(As + u*8) = v;
  }
  __syncthreads();

  const int wave = tid >> 6;
  const int lane = tid & 63;
  const int row = lane & 15;
  const int ko  = (lane >> 4) << 3;
  const int lofs = lane * 8;      // lane offset within a frag (shorts)

  for (int pp = wave; pp < 25; pp += 8) {
    const int j0 = jbase + 2*pp, j1 = j0 + 1;
    const float a00 = a[(i*MM + j0)*NK + 0];
    const float a01 = a[(i*MM + j0)*NK + 1];
    const float a02 = a[(i*MM + j0)*NK + 2];
    const float a10 = a[(i*MM + j1)*NK + 0];
    const float a11 = a[(i*MM + j1)*NK + 1];
    const float a12 = a[(i*MM + j1)*NK + 2];

    const int b00 = (j0*32 + row)*320;
    const int b01 = b00 + 16*320;
    const int b10 = (j1*32 + row)*320;
    const int b11 = b10 + 16*320;

    f32x4 acc[2][3][2][2];
    #pragma unroll
    for (int jj = 0; jj < 2; ++jj)
      #pragma unroll
      for (int kr = 0; kr < 3; ++kr)
        #pragma unroll
        for (int r = 0; r < 2; ++r)
          #pragma unroll
          for (int s = 0; s < 2; ++s)
            acc[jj][kr][r][s] = (f32x4){0.f, 0.f, 0.f, 0.f};

    bf16x8 bufB[2][2][4];   // [dbuf][j][BH0,BH1,BL0,BL1]

    #define LOADB(t, c) do {                                          \
      const int kk_ = (c)*32 + ko;                                    \
      bufB[t][0][0] = *(const bf16x8*)(entH + b00 + kk_);             \
      bufB[t][0][1] = *(const bf16x8*)(entH + b01 + kk_);             \
      bufB[t][0][2] = *(const bf16x8*)(entL + b00 + kk_);             \
      bufB[t][0][3] = *(const bf16x8*)(entL + b01 + kk_);             \
      bufB[t][1][0] = *(const bf16x8*)(entH + b10 + kk_);             \
      bufB[t][1][1] = *(const bf16x8*)(entH + b11 + kk_);             \
      bufB[t][1][2] = *(const bf16x8*)(entL + b10 + kk_);             \
      bufB[t][1][3] = *(const bf16x8*)(entL + b11 + kk_);             \
    } while (0)

    #define STEP(t, c) do {                                           \
      bf16x8 AH[3][2], AL[3][2];                                      \
      _Pragma("unroll")                                               \
      for (int kr_ = 0; kr_ < 3; ++kr_) {                             \
        _Pragma("unroll")                                             \
        for (int rb_ = 0; rb_ < 2; ++rb_) {                           \
          AH[kr_][rb_] = *(const bf16x8*)(As + ((kr_*2 + rb_)*10 + (c))*512 + lofs);       \
          AL[kr_][rb_] = *(const bf16x8*)(As + (((3+kr_)*2 + rb_)*10 + (c))*512 + lofs);   \
        }                                                             \
      }                                                               \
      _Pragma("unroll")                                               \
      for (int jj_ = 0; jj_ < 2; ++jj_) {                             \
        _Pragma("unroll")                                             \
        for (int kr_ = 0; kr_ < 3; ++kr_) {                           \
          _Pragma("unroll")                                           \
          for (int r_ = 0; r_ < 2; ++r_) {                            \
            _Pragma("unroll")                                         \
            for (int s_ = 0; s_ < 2; ++s_) {                          \
              acc[jj_][kr_][r_][s_] = __builtin_amdgcn_mfma_f32_16x16x32_bf16( \
                  AH[kr_][r_], bufB[t][jj_][s_], acc[jj_][kr_][r_][s_], 0, 0, 0); \
              acc[jj_][kr_][r_][s_] = __builtin_amdgcn_mfma_f32_16x16x32_bf16( \
                  AH[kr_][r_], bufB[t][jj_][2 + s_], acc[jj_][kr_][r_][s_], 0, 0, 0); \
              acc[jj_][kr_][r_][s_] = __builtin_amdgcn_mfma_f32_16x16x32_bf16( \
                  AL[kr_][r_], bufB[t][jj_][s_], acc[jj_][kr_][r_][s_], 0, 0, 0); \
            }                                                         \
          }                                                           \
        }                                                             \
      }                                                               \
    } while (0)

    LOADB(0, 0);
    #pragma unroll
    for (int c = 0; c < 10; c += 2) {
      if (c + 1 < 10) LOADB(1, c + 1);
      STEP(0, c);
      if (c + 2 < 10) LOADB(0, c + 2);
      STEP(1, c + 1);
    }
    #undef LOADB
    #undef STEP

    // C/D: col = lane&15 (q), row = (lane>>4)*4 + reg (p)
    const int rbase = (lane >> 4) * 4;
    #pragma unroll
    for (int jj = 0; jj < 2; ++jj) {
      float* ph = phi + (i*MM + (jj ? j1 : j0))*CC*CC;
      const float c0 = jj ? a10 : a00;
      const float c1 = jj ? a11 : a01;
      const float c2 = jj ? a12 : a02;
      #pragma unroll
      for (int r = 0; r < 2; ++r) {
        #pragma unroll
        for (int t = 0; t < 4; ++t) {
          const int p = 16*r + rbase + t;
          if (p < CC) {
            #pragma unroll
            for (int s = 0; s < 2; ++s) {
              const int q = 16*s + row;
              if (q < CC) {
                float v = c0*acc[jj][0][r][s][t] + c1*acc[jj][1][r][s][t] + c2*acc[jj][2][r][s][t];
                ph[p*CC + q] = v;
              }
            }
          }
        }
      }
    }
  }
}

// ---------- zero ----------
__global__ void k_zero(float* __restrict__ p, int n) {
  int idx = blockIdx.x*256 + threadIdx.x;
  if (idx < n) p[idx] = 0.f;
}

// ---------- stot[i,p] = sum_j mbar[j,i,p]  (100 blocks, LDS reduce) ----------
__global__ __launch_bounds__(256) void k_st(const float* __restrict__ mb,
                                            float* __restrict__ stot) {
  int i = blockIdx.x;
  int g = threadIdx.x >> 5;
  int p = threadIdx.x & 31;
  __shared__ float part[8][33];
  float s = 0.f;
  if (p < CC)
    for (int jx = g; jx < MM; jx += 8) s += mb[(jx*MM + i)*CC + p];
  part[g][p] = s;
  __syncthreads();
  if (threadIdx.x < CC) {
    float s2 = 0.f;
    #pragma unroll
    for (int r = 0; r < 8; ++r) s2 += part[r][threadIdx.x];
    stot[i*CC + threadIdx.x] = s2;
  }
}

// ---------- damped LBP update, dense scan: block = (i, 4 j), wave per j ----------
__global__ __launch_bounds__(256) void k_up3(const float* __restrict__ phi,
                                             const float* __restrict__ psi,
                                             const float* __restrict__ stot,
                                             const float* __restrict__ mb_old,
                                             float* __restrict__ mb_new) {
  const int i  = blockIdx.x / 25;
  const int jg = blockIdx.x % 25;
  const int wave = threadIdx.x >> 6;
  const int lane = threadIdx.x & 63;
  const int j = jg*4 + wave;
  const int half = lane >> 5;
  const int q = lane & 31;

  __shared__ float psi_st[32];
  if (threadIdx.x < CC)
    psi_st[threadIdx.x] = psi[i*CC + threadIdx.x] + stot[i*CC + threadIdx.x];
  __syncthreads();

  float csr = (q < CC) ? psi_st[q] - mb_old[(j*MM + i)*CC + q] : -1e30f;

  const float* ph = phi + (i*MM + j)*CC*CC;
  float mv = -1e30f;
  const int p0 = half * 15;
  #pragma unroll
  for (int pp = 0; pp < 15; ++pp) {
    const int p = p0 + pp;
    float v = (q < CC) ? ph[p*CC + q] : -1e30f;
    float cv = __shfl(csr, p, 64);
    mv = fmaxf(mv, v + cv);
  }
  mv = fmaxf(mv, __shfl_xor(mv, 32, 64));
  float x = (q < CC) ? fmaxf(mv, 0.f) : -1e30f;

  float mx = x;
  #pragma unroll
  for (int off = 16; off; off >>= 1) mx = fmaxf(mx, __shfl_xor(mx, off, 64));
  float e = (q < CC) ? expf(x - mx) : 0.f;
  float se = e;
  #pragma unroll
  for (int off = 16; off; off >>= 1) se += __shfl_xor(se, off, 64);

  if (lane < CC) {
    float sm = e / se;
    float old = mb_old[(i*MM + j)*CC + lane];
    mb_new[(i*MM + j)*CC + lane] = logf(0.5f*expf(old) + 0.5f*sm);
  }
}

// ---------- out[i,:] = softmax( psi + sum_j mbar[j,i,:] - mbar[i,i,:] ) ----------
__global__ __launch_bounds__(64) void k_final(const float* __restrict__ psi,
                                              const float* __restrict__ mb,
                                              float* __restrict__ out) {
  int i = blockIdx.x;
  int lane = threadIdx.x;
  float x = -1e30f;
  if (lane < CC) {
    float s = 0.f;
    for (int j = 0; j < MM; ++j) s += mb[(j*MM + i)*CC + lane];
    s -= mb[(i*MM + i)*CC + lane];
    x = psi[i*CC + lane] + s;
  }
  float mx = x;
  #pragma unroll
  for (int off = 16; off; off >>= 1) mx = fmaxf(mx, __shfl_xor(mx, off, 32));
  float e = (lane < CC) ? expf(x - mx) : 0.f;
  float se = e;
  #pragma unroll
  for (int off = 16; off; off >>= 1) se += __shfl_xor(se, off, 32);
  if (lane < CC) out[i*CC + lane] = e / se;
}

extern "C" void kernel_launch(void* const* d_in, const int* in_sizes, int n_in,
                              void* d_out, int out_size, void* d_ws, size_t ws_size,
                              hipStream_t stream) {
  (void)in_sizes; (void)n_in; (void)out_size; (void)ws_size;
  const float* ent  = (const float*)d_in[0];
  const float* fmc  = (const float*)d_in[1];
  const float* W    = (const float*)d_in[2];
  const float* b    = (const float*)d_in[3];
  const float* Bm   = (const float*)d_in[4];
  const float* R    = (const float*)d_in[5];
  const float* Dm   = (const float*)d_in[6];
  float* out = (float*)d_out;
  float* ws  = (float*)d_ws;

  float* f    = ws + 0;
  float* g    = ws + 30000;
  float* psi  = ws + 60000;
  float* t    = ws + 63000;
  float* a    = ws + 153000;
  short* REH  = (short*)(ws + 183000);
  short* REL  = (short*)(ws + 1719000);
  short* entH = (short*)(ws + 3255000);
  short* entL = (short*)(ws + 3767000);
  float* phi  = ws + 4279000;
  float* mbA  = ws + 13279000;
  float* mbB  = ws + 13579000;
  float* stot = ws + 13879000;

  k_zero<<<(MM*MM*CC + 255)/256, 256, 0, stream>>>(mbA, MM*MM*CC);
  k_zero<<<(3072000 + 255)/256, 256, 0, stream>>>(ws + 183000, 3072000);  // REH+REL pads
  k_f  <<<MM, 256, 0, stream>>>(fmc, W, b, f);
  k_g  <<<MM, 256, 0, stream>>>(Bm, f, g);
  k_psi<<<MM, 256, 0, stream>>>(ent, g, psi);
  k_t  <<<NK*MM, 256, 0, stream>>>(Dm, f, t);
  k_a  <<<MM, 256, 0, stream>>>(f, t, a);
  k_esplit<<<MM, 256, 0, stream>>>(ent, entH, entL);
  {
    dim3 grid(5, 24, 3);
    k_re<<<grid, 256, 0, stream>>>(R, ent, REH, REL);
  }
  k_phi5<<<200, 512, 0, stream>>>(a, REH, REL, entH, entL, phi);

  float* cur = mbA; float* nxt = mbB;
  for (int it = 0; it < NLOOP; ++it) {
    k_st<<<MM, 256, 0, stream>>>(cur, stot);
    k_up3<<<MM*25, 256, 0, stream>>>(phi, psi, stot, cur, nxt);
    float* tmp = cur; cur = nxt; nxt = tmp;
  }
  k_final<<<MM, 64, 0, stream>>>(psi, cur, out);
}

// Round 10
// 684.197 us; speedup vs baseline: 1.1686x; 1.1686x over previous
//
#include <hip/hip_runtime.h>
#include <math.h>

#define MM 100     // mentions
#define CC 30      // candidates
#define DE 300     // embedding dim
#define NK 3       // relation types
#define NLOOP 10   // LBP iterations
#define INV_SQRT_D 0.05773502691896258f   // 1/sqrt(300)

typedef __attribute__((ext_vector_type(8))) short bf16x8;
typedef __attribute__((ext_vector_type(4))) float f32x4;

// ws layout (floats):
//  f@0 psi@60000 t@63000 a@153000
//  REH@183000 REL@1719000 (bf16 [k][i][32][320] padded hi/lo)
//  entH@3255000 entL@3767000 (bf16 [j][32][320])
//  phi@4279000  mbarA@13279000 mbarB@13579000 stotbuf@13879000 (11*3000)

__device__ inline void bf16split(float x, short* hi, short* lo) {
  unsigned u  = __float_as_uint(x);
  unsigned hu = u & 0xFFFF0000u;
  float xh = __uint_as_float(hu);
  float rl = x - xh;
  unsigned lu = __float_as_uint(rl);
  lu += 0x7FFFu + ((lu >> 16) & 1u);
  *hi = (short)(hu >> 16);
  *lo = (short)(lu >> 16);
}

// ---------- fused front: f = tanh(fmc W + b); psi = ent·(B f); t_k = D_k f ----------
__global__ __launch_bounds__(256) void k_front(const float* __restrict__ fmc,
                                               const float* __restrict__ W,
                                               const float* __restrict__ b,
                                               const float* __restrict__ Bm,
                                               const float* __restrict__ Dm,
                                               const float* __restrict__ ent,
                                               float* __restrict__ f,
                                               float* __restrict__ psi,
                                               float* __restrict__ t) {
  __shared__ float xs[3*DE];
  __shared__ float fs[DE];
  __shared__ float gs[DE];
  const int m = blockIdx.x;
  for (int e = threadIdx.x; e < 3*DE; e += 256) xs[e] = fmc[m*3*DE + e];
  __syncthreads();
  for (int d = threadIdx.x; d < DE; d += 256) {
    float acc = b[d];
    for (int e = 0; e < 3*DE; ++e) acc = fmaf(xs[e], W[e*DE + d], acc);
    float v = tanhf(acc);
    fs[d] = v;
    f[m*DE + d] = v;
  }
  __syncthreads();
  // g (LDS only)
  for (int d = threadIdx.x; d < DE; d += 256) {
    float acc = 0.f;
    const float* Br = Bm + d*DE;
    for (int e = 0; e < DE; ++e) acc = fmaf(Br[e], fs[e], acc);
    gs[d] = acc;
  }
  // t[k, m, :]
  for (int idx = threadIdx.x; idx < NK*DE; idx += 256) {
    int k = idx / DE, d = idx % DE;
    float acc = 0.f;
    const float* Dr = Dm + (k*DE + d)*DE;
    for (int e = 0; e < DE; ++e) acc = fmaf(Dr[e], fs[e], acc);
    t[(k*MM + m)*DE + d] = acc;
  }
  __syncthreads();
  // psi[m, c] = ent[m,c,:]·gs
  int wave = threadIdx.x >> 6, lane = threadIdx.x & 63;
  for (int c = wave; c < CC; c += 4) {
    float acc = 0.f;
    const float* er = ent + (m*CC + c)*DE;
    for (int d = lane; d < DE; d += 64) acc = fmaf(er[d], gs[d], acc);
    #pragma unroll
    for (int off = 32; off; off >>= 1) acc += __shfl_down(acc, off, 64);
    if (lane == 0) psi[m*CC + c] = acc;
  }
}

// ---------- a[i,j,k] = softmax_k( f_i . t[k,j,:] / sqrt(D) ) ----------
__global__ __launch_bounds__(256) void k_a(const float* __restrict__ f,
                                           const float* __restrict__ t,
                                           float* __restrict__ a) {
  __shared__ float fs[DE];
  int i = blockIdx.x;
  for (int e = threadIdx.x; e < DE; e += 256) fs[e] = f[i*DE + e];
  __syncthreads();
  int wave = threadIdx.x >> 6, lane = threadIdx.x & 63;
  for (int j = wave; j < MM; j += 4) {
    float sk[NK];
    #pragma unroll
    for (int k = 0; k < NK; ++k) {
      float acc = 0.f;
      const float* tr = t + (k*MM + j)*DE;
      for (int d = lane; d < DE; d += 64) acc = fmaf(fs[d], tr[d], acc);
      #pragma unroll
      for (int off = 32; off; off >>= 1) acc += __shfl_down(acc, off, 64);
      sk[k] = acc;
    }
    if (lane == 0) {
      float s0 = sk[0]*INV_SQRT_D, s1 = sk[1]*INV_SQRT_D, s2 = sk[2]*INV_SQRT_D;
      float mx = fmaxf(s0, fmaxf(s1, s2));
      float e0 = expf(s0 - mx), e1 = expf(s1 - mx), e2 = expf(s2 - mx);
      float inv = 1.f / (e0 + e1 + e2);
      float* ar = a + (i*MM + j)*NK;
      ar[0] = e0*inv; ar[1] = e1*inv; ar[2] = e2*inv;
    }
  }
}

// ---------- split ent -> padded bf16 hi/lo [j][32][320] ----------
__global__ __launch_bounds__(256) void k_esplit(const float* __restrict__ ent,
                                                short* __restrict__ entH,
                                                short* __restrict__ entL) {
  int j = blockIdx.x;
  for (int idx = threadIdx.x; idx < 32*320; idx += 256) {
    int q = idx / 320, kk = idx % 320;
    float x = (q < CC && kk < DE) ? ent[(j*CC + q)*DE + kk] : 0.f;
    short h, l;
    bf16split(x, &h, &l);
    entH[(j*32 + q)*320 + kk] = h;
    entL[(j*32 + q)*320 + kk] = l;
  }
}

// ---------- RE GEMM: out = split_bf16( ent_flat[3000,300] @ R_k^T ), padded ----------
__global__ __launch_bounds__(256) void k_re(const float* __restrict__ R,
                                            const float* __restrict__ ent,
                                            short* __restrict__ REH,
                                            short* __restrict__ REL) {
  __shared__ float4 As4[128*5];
  __shared__ float4 Bs4[64*5];
  float* As = (float*)As4;
  float* Bs = (float*)Bs4;

  const int k  = blockIdx.z;
  const int r0 = blockIdx.y * 128;
  const int d0 = blockIdx.x * 64;
  const int tx = threadIdx.x & 15;
  const int ty = threadIdx.x >> 4;
  const float* A  = ent;
  const float* Bk = R + k*DE*DE;

  float acc[8][4];
  #pragma unroll
  for (int r = 0; r < 8; ++r)
    #pragma unroll
    for (int s = 0; s < 4; ++s) acc[r][s] = 0.f;

  for (int e0 = 0; e0 < DE; e0 += 20) {
    #pragma unroll
    for (int it = 0; it < 10; ++it) {
      int idx = threadIdx.x + it*256;
      int row = idx / 20, e = idx % 20;
      int gr = r0 + row;
      As[idx] = (gr < MM*CC) ? A[gr*DE + e0 + e] : 0.f;
    }
    #pragma unroll
    for (int it = 0; it < 5; ++it) {
      int idx = threadIdx.x + it*256;
      int row = idx / 20, e = idx % 20;
      int gd = d0 + row;
      Bs[idx] = (gd < DE) ? Bk[gd*DE + e0 + e] : 0.f;
    }
    __syncthreads();

    #pragma unroll
    for (int v = 0; v < 5; ++v) {
      float4 av[8], bv[4];
      #pragma unroll
      for (int r = 0; r < 8; ++r) av[r] = As4[(ty + 16*r)*5 + v];
      #pragma unroll
      for (int s = 0; s < 4; ++s) bv[s] = Bs4[(tx + 16*s)*5 + v];
      #pragma unroll
      for (int r = 0; r < 8; ++r)
        #pragma unroll
        for (int s = 0; s < 4; ++s) {
          acc[r][s] = fmaf(av[r].x, bv[s].x, acc[r][s]);
          acc[r][s] = fmaf(av[r].y, bv[s].y, acc[r][s]);
          acc[r][s] = fmaf(av[r].z, bv[s].z, acc[r][s]);
          acc[r][s] = fmaf(av[r].w, bv[s].w, acc[r][s]);
        }
    }
    __syncthreads();
  }

  #pragma unroll
  for (int r = 0; r < 8; ++r) {
    int gr = r0 + ty + 16*r;
    if (gr < MM*CC) {
      int i = gr / CC, p = gr % CC;
      #pragma unroll
      for (int s = 0; s < 4; ++s) {
        int gd = d0 + tx + 16*s;
        if (gd < DE) {
          size_t idx = (((size_t)k*MM + i)*32 + p)*320 + gd;
          short h, l;
          bf16split(acc[r][s], &h, &l);
          REH[idx] = h;
          REL[idx] = l;
        }
      }
    }
  }
}

// ---------- phi via MFMA (R8-verified k_phi4, reverted exactly) ----------
__global__ __launch_bounds__(256) void k_phi4(const float* __restrict__ a,
                                              const short* __restrict__ REH,
                                              const short* __restrict__ REL,
                                              const short* __restrict__ entH,
                                              const short* __restrict__ entL,
                                              float* __restrict__ phi) {
  const int bs = blockIdx.x;
  int i, jg;
  if (bs < 2400) {
    int x = bs & 7;
    int s = bs >> 3;
    jg = s / 12;
    i  = x*12 + s % 12;
  } else {
    int r = bs - 2400;
    i  = 96 + (r & 3);
    jg = r >> 2;
  }
  const int wave = threadIdx.x >> 6;
  const int lane = threadIdx.x & 63;
  const int j = jg*4 + wave;

  const int row = lane & 15;
  const int ko  = (lane >> 4) << 3;

  const float a0 = a[(i*MM + j)*NK + 0];
  const float a1 = a[(i*MM + j)*NK + 1];
  const float a2 = a[(i*MM + j)*NK + 2];

  const int b0 = (j*32 + row)*320;
  const int b1 = b0 + 16*320;
  const int ar0 = row*320;
  const int ar1 = ar0 + 16*320;
  const int aib = i*32*320;
  const int RELSTRIDE = MM*32*320;

  f32x4 acc[3][2][2];
  #pragma unroll
  for (int kr = 0; kr < 3; ++kr)
    #pragma unroll
    for (int r = 0; r < 2; ++r)
      #pragma unroll
      for (int s = 0; s < 2; ++s)
        acc[kr][r][s] = (f32x4){0.f, 0.f, 0.f, 0.f};

  bf16x8 bufA[2][3][4];
  bf16x8 bufB[2][4];

  #define LOADC(t, c) do {                                            \
    const int kk_ = (c)*32 + ko;                                      \
    bufB[t][0] = *(const bf16x8*)(entH + b0 + kk_);                   \
    bufB[t][1] = *(const bf16x8*)(entH + b1 + kk_);                   \
    bufB[t][2] = *(const bf16x8*)(entL + b0 + kk_);                   \
    bufB[t][3] = *(const bf16x8*)(entL + b1 + kk_);                   \
    _Pragma("unroll")                                                 \
    for (int kr_ = 0; kr_ < 3; ++kr_) {                               \
      const int ab_ = aib + kr_*RELSTRIDE + kk_;                      \
      bufA[t][kr_][0] = *(const bf16x8*)(REH + ab_ + ar0);            \
      bufA[t][kr_][1] = *(const bf16x8*)(REH + ab_ + ar1);            \
      bufA[t][kr_][2] = *(const bf16x8*)(REL + ab_ + ar0);            \
      bufA[t][kr_][3] = *(const bf16x8*)(REL + ab_ + ar1);            \
    }                                                                 \
  } while (0)

  #define COMPUTE(t) do {                                             \
    _Pragma("unroll")                                                 \
    for (int kr_ = 0; kr_ < 3; ++kr_) {                               \
      _Pragma("unroll")                                               \
      for (int r_ = 0; r_ < 2; ++r_) {                                \
        _Pragma("unroll")                                             \
        for (int s_ = 0; s_ < 2; ++s_) {                              \
          acc[kr_][r_][s_] = __builtin_amdgcn_mfma_f32_16x16x32_bf16( \
              bufA[t][kr_][r_], bufB[t][s_], acc[kr_][r_][s_], 0, 0, 0); \
          acc[kr_][r_][s_] = __builtin_amdgcn_mfma_f32_16x16x32_bf16( \
              bufA[t][kr_][r_], bufB[t][2 + s_], acc[kr_][r_][s_], 0, 0, 0); \
          acc[kr_][r_][s_] = __builtin_amdgcn_mfma_f32_16x16x32_bf16( \
              bufA[t][kr_][2 + r_], bufB[t][s_], acc[kr_][r_][s_], 0, 0, 0); \
        }                                                             \
      }                                                               \
    }                                                                 \
  } while (0)

  LOADC(0, 0);
  #pragma unroll
  for (int c = 0; c < 10; c += 2) {
    if (c + 1 < 10) LOADC(1, c + 1);
    COMPUTE(0);
    if (c + 2 < 10) LOADC(0, c + 2);
    COMPUTE(1);
  }
  #undef LOADC
  #undef COMPUTE

  float* ph = phi + (i*MM + j)*CC*CC;
  const int rbase = (lane >> 4) * 4;
  #pragma unroll
  for (int r = 0; r < 2; ++r) {
    #pragma unroll
    for (int t = 0; t < 4; ++t) {
      const int p = 16*r + rbase + t;
      if (p < CC) {
        #pragma unroll
        for (int s = 0; s < 2; ++s) {
          const int q = 16*s + row;
          if (q < CC) {
            float v = a0*acc[0][r][s][t] + a1*acc[1][r][s][t] + a2*acc[2][r][s][t];
            ph[p*CC + q] = v;
          }
        }
      }
    }
  }
}

// ---------- zero ----------
__global__ void k_zero(float* __restrict__ p, int n) {
  int idx = blockIdx.x*256 + threadIdx.x;
  if (idx < n) p[idx] = 0.f;
}

// ---------- damped LBP update + fused stot accumulation (atomics) ----------
// block = (i, 4 j), wave per j. Reads stot_cur[i,:]; writes nxt[i,j,:] and
// atomicAdds the same values into stot_next[j,:] (stot[x] = sum_k mb[k,x]).
__global__ __launch_bounds__(256) void k_up4(const float* __restrict__ phi,
                                             const float* __restrict__ psi,
                                             const float* __restrict__ stot_cur,
                                             float* __restrict__ stot_next,
                                             const float* __restrict__ mb_old,
                                             float* __restrict__ mb_new) {
  const int i  = blockIdx.x / 25;
  const int jg = blockIdx.x % 25;
  const int wave = threadIdx.x >> 6;
  const int lane = threadIdx.x & 63;
  const int j = jg*4 + wave;
  const int half = lane >> 5;
  const int q = lane & 31;

  __shared__ float psi_st[32];
  if (threadIdx.x < CC)
    psi_st[threadIdx.x] = psi[i*CC + threadIdx.x] + stot_cur[i*CC + threadIdx.x];
  __syncthreads();

  float csr = (q < CC) ? psi_st[q] - mb_old[(j*MM + i)*CC + q] : -1e30f;

  const float* ph = phi + (i*MM + j)*CC*CC;
  float mv = -1e30f;
  const int p0 = half * 15;
  #pragma unroll
  for (int pp = 0; pp < 15; ++pp) {
    const int p = p0 + pp;
    float v = (q < CC) ? ph[p*CC + q] : -1e30f;
    float cv = __shfl(csr, p, 64);
    mv = fmaxf(mv, v + cv);
  }
  mv = fmaxf(mv, __shfl_xor(mv, 32, 64));
  float x = (q < CC) ? fmaxf(mv, 0.f) : -1e30f;

  float mx = x;
  #pragma unroll
  for (int off = 16; off; off >>= 1) mx = fmaxf(mx, __shfl_xor(mx, off, 64));
  float e = (q < CC) ? expf(x - mx) : 0.f;
  float se = e;
  #pragma unroll
  for (int off = 16; off; off >>= 1) se += __shfl_xor(se, off, 64);

  if (lane < CC) {
    float sm = e / se;
    float old = mb_old[(i*MM + j)*CC + lane];
    float nv = logf(0.5f*expf(old) + 0.5f*sm);
    mb_new[(i*MM + j)*CC + lane] = nv;
    atomicAdd(stot_next + j*CC + lane, nv);   // contributes to stot[j] next iter
  }
}

// ---------- out[i,:] = softmax( psi + stot_final[i,:] - mbar[i,i,:] ) ----------
__global__ __launch_bounds__(64) void k_final(const float* __restrict__ psi,
                                              const float* __restrict__ stotN,
                                              const float* __restrict__ mb,
                                              float* __restrict__ out) {
  int i = blockIdx.x;
  int lane = threadIdx.x;
  float x = -1e30f;
  if (lane < CC)
    x = psi[i*CC + lane] + stotN[i*CC + lane] - mb[(i*MM + i)*CC + lane];
  float mx = x;
  #pragma unroll
  for (int off = 16; off; off >>= 1) mx = fmaxf(mx, __shfl_xor(mx, off, 32));
  float e = (lane < CC) ? expf(x - mx) : 0.f;
  float se = e;
  #pragma unroll
  for (int off = 16; off; off >>= 1) se += __shfl_xor(se, off, 32);
  if (lane < CC) out[i*CC + lane] = e / se;
}

extern "C" void kernel_launch(void* const* d_in, const int* in_sizes, int n_in,
                              void* d_out, int out_size, void* d_ws, size_t ws_size,
                              hipStream_t stream) {
  (void)in_sizes; (void)n_in; (void)out_size; (void)ws_size;
  const float* ent  = (const float*)d_in[0];
  const float* fmc  = (const float*)d_in[1];
  const float* W    = (const float*)d_in[2];
  const float* b    = (const float*)d_in[3];
  const float* Bm   = (const float*)d_in[4];
  const float* R    = (const float*)d_in[5];
  const float* Dm   = (const float*)d_in[6];
  float* out = (float*)d_out;
  float* ws  = (float*)d_ws;

  float* f    = ws + 0;
  float* psi  = ws + 60000;
  float* t    = ws + 63000;
  float* a    = ws + 153000;
  short* REH  = (short*)(ws + 183000);
  short* REL  = (short*)(ws + 1719000);
  short* entH = (short*)(ws + 3255000);
  short* entL = (short*)(ws + 3767000);
  float* phi  = ws + 4279000;
  float* mbA  = ws + 13279000;
  float* mbB  = ws + 13579000;
  float* stotbuf = ws + 13879000;   // (NLOOP+1)*3000 floats

  // zero mbA + mbB + stotbuf in one shot (contiguous 633000 floats)
  k_zero<<<(633000 + 255)/256, 256, 0, stream>>>(mbA, 633000);
  k_zero<<<(3072000 + 255)/256, 256, 0, stream>>>(ws + 183000, 3072000);  // RE pads

  k_front<<<MM, 256, 0, stream>>>(fmc, W, b, Bm, Dm, ent, f, psi, t);
  k_a    <<<MM, 256, 0, stream>>>(f, t, a);
  k_esplit<<<MM, 256, 0, stream>>>(ent, entH, entL);
  {
    dim3 grid(5, 24, 3);
    k_re<<<grid, 256, 0, stream>>>(R, ent, REH, REL);
  }
  k_phi4<<<2500, 256, 0, stream>>>(a, REH, REL, entH, entL, phi);

  float* cur = mbA; float* nxt = mbB;
  for (int it = 0; it < NLOOP; ++it) {
    k_up4<<<MM*25, 256, 0, stream>>>(phi, psi,
                                     stotbuf + it*MM*CC,
                                     stotbuf + (it+1)*MM*CC,
                                     cur, nxt);
    float* tmp = cur; cur = nxt; nxt = tmp;
  }
  k_final<<<MM, 64, 0, stream>>>(psi, stotbuf + NLOOP*MM*CC, cur, out);
}

// Round 11
// 587.964 us; speedup vs baseline: 1.3599x; 1.1637x over previous
//
#include <hip/hip_runtime.h>
#include <math.h>

#define MM 100     // mentions
#define CC 30      // candidates
#define DE 300     // embedding dim
#define NK 3       // relation types
#define NLOOP 10   // LBP iterations
#define INV_SQRT_D 0.05773502691896258f   // 1/sqrt(300)

typedef __attribute__((ext_vector_type(8))) short bf16x8;
typedef __attribute__((ext_vector_type(4))) float f32x4;

// ws layout (floats):
//  f@0 psi@60000 t@63000 a@153000
//  REH@183000 REL@1719000 (bf16 [k][i][32][320] padded hi/lo)
//  entH@3255000 entL@3767000 (bf16 [j][32][320])
//  phi@4279000  mbarA@13279000 mbarB@13579000 stotbuf@13879000 (11*3000)

__device__ inline void bf16split(float x, short* hi, short* lo) {
  unsigned u  = __float_as_uint(x);
  unsigned hu = u & 0xFFFF0000u;
  float xh = __uint_as_float(hu);
  float rl = x - xh;
  unsigned lu = __float_as_uint(rl);
  lu += 0x7FFFu + ((lu >> 16) & 1u);
  *hi = (short)(hu >> 16);
  *lo = (short)(lu >> 16);
}

// ---------- fused front: f = tanh(fmc W + b); psi = ent·(B f); t_k = D_k f ----------
__global__ __launch_bounds__(256) void k_front(const float* __restrict__ fmc,
                                               const float* __restrict__ W,
                                               const float* __restrict__ b,
                                               const float* __restrict__ Bm,
                                               const float* __restrict__ Dm,
                                               const float* __restrict__ ent,
                                               float* __restrict__ f,
                                               float* __restrict__ psi,
                                               float* __restrict__ t) {
  __shared__ float xs[3*DE];
  __shared__ float fs[DE];
  __shared__ float gs[DE];
  const int m = blockIdx.x;
  for (int e = threadIdx.x; e < 3*DE; e += 256) xs[e] = fmc[m*3*DE + e];
  __syncthreads();
  for (int d = threadIdx.x; d < DE; d += 256) {
    float acc = b[d];
    for (int e = 0; e < 3*DE; ++e) acc = fmaf(xs[e], W[e*DE + d], acc);
    float v = tanhf(acc);
    fs[d] = v;
    f[m*DE + d] = v;
  }
  __syncthreads();
  for (int d = threadIdx.x; d < DE; d += 256) {
    float acc = 0.f;
    const float* Br = Bm + d*DE;
    for (int e = 0; e < DE; ++e) acc = fmaf(Br[e], fs[e], acc);
    gs[d] = acc;
  }
  for (int idx = threadIdx.x; idx < NK*DE; idx += 256) {
    int k = idx / DE, d = idx % DE;
    float acc = 0.f;
    const float* Dr = Dm + (k*DE + d)*DE;
    for (int e = 0; e < DE; ++e) acc = fmaf(Dr[e], fs[e], acc);
    t[(k*MM + m)*DE + d] = acc;
  }
  __syncthreads();
  int wave = threadIdx.x >> 6, lane = threadIdx.x & 63;
  for (int c = wave; c < CC; c += 4) {
    float acc = 0.f;
    const float* er = ent + (m*CC + c)*DE;
    for (int d = lane; d < DE; d += 64) acc = fmaf(er[d], gs[d], acc);
    #pragma unroll
    for (int off = 32; off; off >>= 1) acc += __shfl_down(acc, off, 64);
    if (lane == 0) psi[m*CC + c] = acc;
  }
}

// ---------- a[i,j,k] = softmax_k( f_i . t[k,j,:] / sqrt(D) ) ----------
__global__ __launch_bounds__(256) void k_a(const float* __restrict__ f,
                                           const float* __restrict__ t,
                                           float* __restrict__ a) {
  __shared__ float fs[DE];
  int i = blockIdx.x;
  for (int e = threadIdx.x; e < DE; e += 256) fs[e] = f[i*DE + e];
  __syncthreads();
  int wave = threadIdx.x >> 6, lane = threadIdx.x & 63;
  for (int j = wave; j < MM; j += 4) {
    float sk[NK];
    #pragma unroll
    for (int k = 0; k < NK; ++k) {
      float acc = 0.f;
      const float* tr = t + (k*MM + j)*DE;
      for (int d = lane; d < DE; d += 64) acc = fmaf(fs[d], tr[d], acc);
      #pragma unroll
      for (int off = 32; off; off >>= 1) acc += __shfl_down(acc, off, 64);
      sk[k] = acc;
    }
    if (lane == 0) {
      float s0 = sk[0]*INV_SQRT_D, s1 = sk[1]*INV_SQRT_D, s2 = sk[2]*INV_SQRT_D;
      float mx = fmaxf(s0, fmaxf(s1, s2));
      float e0 = expf(s0 - mx), e1 = expf(s1 - mx), e2 = expf(s2 - mx);
      float inv = 1.f / (e0 + e1 + e2);
      float* ar = a + (i*MM + j)*NK;
      ar[0] = e0*inv; ar[1] = e1*inv; ar[2] = e2*inv;
    }
  }
}

// ---------- split ent -> padded bf16 hi/lo [j][32][320] ----------
__global__ __launch_bounds__(256) void k_esplit(const float* __restrict__ ent,
                                                short* __restrict__ entH,
                                                short* __restrict__ entL) {
  int j = blockIdx.x;
  for (int idx = threadIdx.x; idx < 32*320; idx += 256) {
    int q = idx / 320, kk = idx % 320;
    float x = (q < CC && kk < DE) ? ent[(j*CC + q)*DE + kk] : 0.f;
    short h, l;
    bf16split(x, &h, &l);
    entH[(j*32 + q)*320 + kk] = h;
    entL[(j*32 + q)*320 + kk] = l;
  }
}

// ---------- RE GEMM: out = split_bf16( ent_flat[3000,300] @ R_k^T ), padded ----------
__global__ __launch_bounds__(256) void k_re(const float* __restrict__ R,
                                            const float* __restrict__ ent,
                                            short* __restrict__ REH,
                                            short* __restrict__ REL) {
  __shared__ float4 As4[128*5];
  __shared__ float4 Bs4[64*5];
  float* As = (float*)As4;
  float* Bs = (float*)Bs4;

  const int k  = blockIdx.z;
  const int r0 = blockIdx.y * 128;
  const int d0 = blockIdx.x * 64;
  const int tx = threadIdx.x & 15;
  const int ty = threadIdx.x >> 4;
  const float* A  = ent;
  const float* Bk = R + k*DE*DE;

  float acc[8][4];
  #pragma unroll
  for (int r = 0; r < 8; ++r)
    #pragma unroll
    for (int s = 0; s < 4; ++s) acc[r][s] = 0.f;

  for (int e0 = 0; e0 < DE; e0 += 20) {
    #pragma unroll
    for (int it = 0; it < 10; ++it) {
      int idx = threadIdx.x + it*256;
      int row = idx / 20, e = idx % 20;
      int gr = r0 + row;
      As[idx] = (gr < MM*CC) ? A[gr*DE + e0 + e] : 0.f;
    }
    #pragma unroll
    for (int it = 0; it < 5; ++it) {
      int idx = threadIdx.x + it*256;
      int row = idx / 20, e = idx % 20;
      int gd = d0 + row;
      Bs[idx] = (gd < DE) ? Bk[gd*DE + e0 + e] : 0.f;
    }
    __syncthreads();

    #pragma unroll
    for (int v = 0; v < 5; ++v) {
      float4 av[8], bv[4];
      #pragma unroll
      for (int r = 0; r < 8; ++r) av[r] = As4[(ty + 16*r)*5 + v];
      #pragma unroll
      for (int s = 0; s < 4; ++s) bv[s] = Bs4[(tx + 16*s)*5 + v];
      #pragma unroll
      for (int r = 0; r < 8; ++r)
        #pragma unroll
        for (int s = 0; s < 4; ++s) {
          acc[r][s] = fmaf(av[r].x, bv[s].x, acc[r][s]);
          acc[r][s] = fmaf(av[r].y, bv[s].y, acc[r][s]);
          acc[r][s] = fmaf(av[r].z, bv[s].z, acc[r][s]);
          acc[r][s] = fmaf(av[r].w, bv[s].w, acc[r][s]);
        }
    }
    __syncthreads();
  }

  #pragma unroll
  for (int r = 0; r < 8; ++r) {
    int gr = r0 + ty + 16*r;
    if (gr < MM*CC) {
      int i = gr / CC, p = gr % CC;
      #pragma unroll
      for (int s = 0; s < 4; ++s) {
        int gd = d0 + tx + 16*s;
        if (gd < DE) {
          size_t idx = (((size_t)k*MM + i)*32 + p)*320 + gd;
          short h, l;
          bf16split(acc[r][s], &h, &l);
          REH[idx] = h;
          REL[idx] = l;
        }
      }
    }
  }
}

// ---------- phi via MFMA: LDS-staged A (m97 pattern), double-buffered ----------
// Block = (i, 4 j) as k_phi4. A(i) c-slice (12 frags x 1024 B = 12 KB) staged
// in LDS, shared by all 4 waves; x2 buffers = 24 KB. Wave w stages frags
// 3w..3w+2 (reg-staged ds_write_b128). A-reads become conflict-free
// ds_read_b128; per-thread global A traffic drops 4x. B per-wave from global.
// frag id: fr = hl*6 + kr*2 + rb  (hl: 0=hi 1=lo).
__global__ __launch_bounds__(256) void k_phi6(const float* __restrict__ a,
                                              const short* __restrict__ REH,
                                              const short* __restrict__ REL,
                                              const short* __restrict__ entH,
                                              const short* __restrict__ entL,
                                              float* __restrict__ phi) {
  __shared__ short As[2][12*512];   // 24,576 B
  const int bs = blockIdx.x;
  int i, jg;
  if (bs < 2400) {
    int x = bs & 7;
    int s = bs >> 3;
    jg = s / 12;
    i  = x*12 + s % 12;
  } else {
    int r = bs - 2400;
    i  = 96 + (r & 3);
    jg = r >> 2;
  }
  const int wave = threadIdx.x >> 6;
  const int lane = threadIdx.x & 63;
  const int j = jg*4 + wave;

  const int row = lane & 15;
  const int g8  = (lane >> 4) << 3;   // 0,8,16,24 (element offset within 32-k slice)

  const float a0 = a[(i*MM + j)*NK + 0];
  const float a1 = a[(i*MM + j)*NK + 1];
  const float a2 = a[(i*MM + j)*NK + 2];

  const int b0 = (j*32 + row)*320;
  const int b1 = b0 + 16*320;

  // this wave's 3 staging frags: source per-lane base (shorts), +c*32 per c
  const short* asrc[3];
  short* adst[3];   // LDS dst (buffer 0); buffer 1 = +12*512
  #pragma unroll
  for (int q = 0; q < 3; ++q) {
    const int fr = 3*wave + q;
    const int b6 = fr % 6;
    const int kr = b6 >> 1, rb = b6 & 1;
    const short* src = (fr < 6) ? REH : REL;
    asrc[q] = src + ((kr*MM + i)*32 + rb*16 + row)*320 + g8;
    adst[q] = (short*)As + fr*512 + lane*8;
  }

  f32x4 acc[3][2][2];
  #pragma unroll
  for (int kr = 0; kr < 3; ++kr)
    #pragma unroll
    for (int r = 0; r < 2; ++r)
      #pragma unroll
      for (int s = 0; s < 2; ++s)
        acc[kr][r][s] = (f32x4){0.f, 0.f, 0.f, 0.f};

  // prologue: stage c=0 into buffer 0
  {
    int4 v0 = *(const int4*)(asrc[0]);
    int4 v1 = *(const int4*)(asrc[1]);
    int4 v2 = *(const int4*)(asrc[2]);
    *(int4*)(adst[0]) = v0;
    *(int4*)(adst[1]) = v1;
    *(int4*)(adst[2]) = v2;
  }
  __syncthreads();

  int cur = 0;
  for (int c = 0; c < 10; ++c) {
    // prefetch A(c+1) into regs (global, overlaps compute below)
    int4 v0, v1, v2;
    if (c < 9) {
      v0 = *(const int4*)(asrc[0] + (c+1)*32);
      v1 = *(const int4*)(asrc[1] + (c+1)*32);
      v2 = *(const int4*)(asrc[2] + (c+1)*32);
    }
    // B for this c (per-wave, from L2-pinned ent)
    const int kk = c*32 + g8;
    bf16x8 BH0 = *(const bf16x8*)(entH + b0 + kk);
    bf16x8 BH1 = *(const bf16x8*)(entH + b1 + kk);
    bf16x8 BL0 = *(const bf16x8*)(entL + b0 + kk);
    bf16x8 BL1 = *(const bf16x8*)(entL + b1 + kk);

    const short* Ab = (const short*)As + cur*12*512 + lane*8;
    #pragma unroll
    for (int kr = 0; kr < 3; ++kr) {
      bf16x8 AH0 = *(const bf16x8*)(Ab + (kr*2 + 0)*512);
      bf16x8 AH1 = *(const bf16x8*)(Ab + (kr*2 + 1)*512);
      bf16x8 AL0 = *(const bf16x8*)(Ab + (6 + kr*2 + 0)*512);
      bf16x8 AL1 = *(const bf16x8*)(Ab + (6 + kr*2 + 1)*512);
      // r=0 (A rows 0-15), r=1 (16-31); s=0 (B rows 0-15), s=1 (16-31)
      acc[kr][0][0] = __builtin_amdgcn_mfma_f32_16x16x32_bf16(AH0, BH0, acc[kr][0][0], 0, 0, 0);
      acc[kr][0][0] = __builtin_amdgcn_mfma_f32_16x16x32_bf16(AH0, BL0, acc[kr][0][0], 0, 0, 0);
      acc[kr][0][0] = __builtin_amdgcn_mfma_f32_16x16x32_bf16(AL0, BH0, acc[kr][0][0], 0, 0, 0);
      acc[kr][0][1] = __builtin_amdgcn_mfma_f32_16x16x32_bf16(AH0, BH1, acc[kr][0][1], 0, 0, 0);
      acc[kr][0][1] = __builtin_amdgcn_mfma_f32_16x16x32_bf16(AH0, BL1, acc[kr][0][1], 0, 0, 0);
      acc[kr][0][1] = __builtin_amdgcn_mfma_f32_16x16x32_bf16(AL0, BH1, acc[kr][0][1], 0, 0, 0);
      acc[kr][1][0] = __builtin_amdgcn_mfma_f32_16x16x32_bf16(AH1, BH0, acc[kr][1][0], 0, 0, 0);
      acc[kr][1][0] = __builtin_amdgcn_mfma_f32_16x16x32_bf16(AH1, BL0, acc[kr][1][0], 0, 0, 0);
      acc[kr][1][0] = __builtin_amdgcn_mfma_f32_16x16x32_bf16(AL1, BH0, acc[kr][1][0], 0, 0, 0);
      acc[kr][1][1] = __builtin_amdgcn_mfma_f32_16x16x32_bf16(AH1, BH1, acc[kr][1][1], 0, 0, 0);
      acc[kr][1][1] = __builtin_amdgcn_mfma_f32_16x16x32_bf16(AH1, BL1, acc[kr][1][1], 0, 0, 0);
      acc[kr][1][1] = __builtin_amdgcn_mfma_f32_16x16x32_bf16(AL1, BH1, acc[kr][1][1], 0, 0, 0);
    }

    if (c < 9) {
      short* dst = (short*)As + (cur^1)*12*512;
      *(int4*)(dst + (3*wave + 0)*512 + lane*8) = v0;
      *(int4*)(dst + (3*wave + 1)*512 + lane*8) = v1;
      *(int4*)(dst + (3*wave + 2)*512 + lane*8) = v2;
      __syncthreads();
      cur ^= 1;
    }
  }

  // C/D: col = lane&15 (q), row = (lane>>4)*4 + reg (p)
  float* ph = phi + (i*MM + j)*CC*CC;
  const int rbase = (lane >> 4) * 4;
  #pragma unroll
  for (int r = 0; r < 2; ++r) {
    #pragma unroll
    for (int t = 0; t < 4; ++t) {
      const int p = 16*r + rbase + t;
      if (p < CC) {
        #pragma unroll
        for (int s = 0; s < 2; ++s) {
          const int q = 16*s + row;
          if (q < CC) {
            float v = a0*acc[0][r][s][t] + a1*acc[1][r][s][t] + a2*acc[2][r][s][t];
            ph[p*CC + q] = v;
          }
        }
      }
    }
  }
}

// ---------- zero ----------
__global__ void k_zero(float* __restrict__ p, int n) {
  int idx = blockIdx.x*256 + threadIdx.x;
  if (idx < n) p[idx] = 0.f;
}

// ---------- damped LBP update + fused stot accumulation (atomics) ----------
__global__ __launch_bounds__(256) void k_up4(const float* __restrict__ phi,
                                             const float* __restrict__ psi,
                                             const float* __restrict__ stot_cur,
                                             float* __restrict__ stot_next,
                                             const float* __restrict__ mb_old,
                                             float* __restrict__ mb_new) {
  const int i  = blockIdx.x / 25;
  const int jg = blockIdx.x % 25;
  const int wave = threadIdx.x >> 6;
  const int lane = threadIdx.x & 63;
  const int j = jg*4 + wave;
  const int half = lane >> 5;
  const int q = lane & 31;

  __shared__ float psi_st[32];
  if (threadIdx.x < CC)
    psi_st[threadIdx.x] = psi[i*CC + threadIdx.x] + stot_cur[i*CC + threadIdx.x];
  __syncthreads();

  float csr = (q < CC) ? psi_st[q] - mb_old[(j*MM + i)*CC + q] : -1e30f;

  const float* ph = phi + (i*MM + j)*CC*CC;
  float mv = -1e30f;
  const int p0 = half * 15;
  #pragma unroll
  for (int pp = 0; pp < 15; ++pp) {
    const int p = p0 + pp;
    float v = (q < CC) ? ph[p*CC + q] : -1e30f;
    float cv = __shfl(csr, p, 64);
    mv = fmaxf(mv, v + cv);
  }
  mv = fmaxf(mv, __shfl_xor(mv, 32, 64));
  float x = (q < CC) ? fmaxf(mv, 0.f) : -1e30f;

  float mx = x;
  #pragma unroll
  for (int off = 16; off; off >>= 1) mx = fmaxf(mx, __shfl_xor(mx, off, 64));
  float e = (q < CC) ? expf(x - mx) : 0.f;
  float se = e;
  #pragma unroll
  for (int off = 16; off; off >>= 1) se += __shfl_xor(se, off, 64);

  if (lane < CC) {
    float sm = e / se;
    float old = mb_old[(i*MM + j)*CC + lane];
    float nv = logf(0.5f*expf(old) + 0.5f*sm);
    mb_new[(i*MM + j)*CC + lane] = nv;
    atomicAdd(stot_next + j*CC + lane, nv);
  }
}

// ---------- out[i,:] = softmax( psi + stot_final[i,:] - mbar[i,i,:] ) ----------
__global__ __launch_bounds__(64) void k_final(const float* __restrict__ psi,
                                              const float* __restrict__ stotN,
                                              const float* __restrict__ mb,
                                              float* __restrict__ out) {
  int i = blockIdx.x;
  int lane = threadIdx.x;
  float x = -1e30f;
  if (lane < CC)
    x = psi[i*CC + lane] + stotN[i*CC + lane] - mb[(i*MM + i)*CC + lane];
  float mx = x;
  #pragma unroll
  for (int off = 16; off; off >>= 1) mx = fmaxf(mx, __shfl_xor(mx, off, 32));
  float e = (lane < CC) ? expf(x - mx) : 0.f;
  float se = e;
  #pragma unroll
  for (int off = 16; off; off >>= 1) se += __shfl_xor(se, off, 32);
  if (lane < CC) out[i*CC + lane] = e / se;
}

extern "C" void kernel_launch(void* const* d_in, const int* in_sizes, int n_in,
                              void* d_out, int out_size, void* d_ws, size_t ws_size,
                              hipStream_t stream) {
  (void)in_sizes; (void)n_in; (void)out_size; (void)ws_size;
  const float* ent  = (const float*)d_in[0];
  const float* fmc  = (const float*)d_in[1];
  const float* W    = (const float*)d_in[2];
  const float* b    = (const float*)d_in[3];
  const float* Bm   = (const float*)d_in[4];
  const float* R    = (const float*)d_in[5];
  const float* Dm   = (const float*)d_in[6];
  float* out = (float*)d_out;
  float* ws  = (float*)d_ws;

  float* f    = ws + 0;
  float* psi  = ws + 60000;
  float* t    = ws + 63000;
  float* a    = ws + 153000;
  short* REH  = (short*)(ws + 183000);
  short* REL  = (short*)(ws + 1719000);
  short* entH = (short*)(ws + 3255000);
  short* entL = (short*)(ws + 3767000);
  float* phi  = ws + 4279000;
  float* mbA  = ws + 13279000;
  float* mbB  = ws + 13579000;
  float* stotbuf = ws + 13879000;   // (NLOOP+1)*3000 floats

  k_zero<<<(633000 + 255)/256, 256, 0, stream>>>(mbA, 633000);
  k_zero<<<(3072000 + 255)/256, 256, 0, stream>>>(ws + 183000, 3072000);  // RE pads

  k_front<<<MM, 256, 0, stream>>>(fmc, W, b, Bm, Dm, ent, f, psi, t);
  k_a    <<<MM, 256, 0, stream>>>(f, t, a);
  k_esplit<<<MM, 256, 0, stream>>>(ent, entH, entL);
  {
    dim3 grid(5, 24, 3);
    k_re<<<grid, 256, 0, stream>>>(R, ent, REH, REL);
  }
  k_phi6<<<2500, 256, 0, stream>>>(a, REH, REL, entH, entL, phi);

  float* cur = mbA; float* nxt = mbB;
  for (int it = 0; it < NLOOP; ++it) {
    k_up4<<<MM*25, 256, 0, stream>>>(phi, psi,
                                     stotbuf + it*MM*CC,
                                     stotbuf + (it+1)*MM*CC,
                                     cur, nxt);
    float* tmp = cur; cur = nxt; nxt = tmp;
  }
  k_final<<<MM, 64, 0, stream>>>(psi, stotbuf + NLOOP*MM*CC, cur, out);
}